// Round 8
// baseline (412.235 us; speedup 1.0000x reference)
//
#include <hip/hip_runtime.h>
#include <hip/hip_cooperative_groups.h>
#include <stdint.h>

// ---- problem constants (PointRCNN RPN, KITTI Car) ----
#define BN 4
#define NPTS 16384
#define REGC 76
#define PRE 2250
#define PRE_PAD 2304          // 18*128, padded stride
#define POST 128
#define NBINS 4096            // 12-bit histogram on flipped float key
#define SORTN 4096            // candidate-set capacity
#define ECAP 4096             // max suppression edges per image
#define NMS_T 0.8f
#define TI 18                 // ceil(PRE/128)
#define NTRI 171              // TI*(TI+1)/2 upper-triangle tiles per image
#define SZB (BN * PRE_PAD)    // per-array stride for BEV SoA
#define GRID 512              // cooperative grid (needs only 2 blocks/CU)
#define BLK 256
#define SEGCAP 2048           // LDS bin-segment capacity (u64)

namespace cg = cooperative_groups;

// Order-preserving float->uint flip: ascending uint == ascending float.
__device__ __forceinline__ uint32_t flip_f32(float f) {
  uint32_t u = __float_as_uint(f);
  return (u & 0x80000000u) ? ~u : (u | 0x80000000u);
}
__device__ __forceinline__ float unflip_f32(uint32_t k) {
  uint32_t u = (k & 0x80000000u) ? (k & 0x7FFFFFFFu) : ~k;
  return __uint_as_float(u);
}
__device__ __forceinline__ int argmax12(const float* a) {
  int b = 0;
  float m = a[0];
#pragma unroll
  for (int c = 1; c < 12; ++c)
    if (a[c] > m) { m = a[c]; b = c; }   // strict > == first-occurrence argmax
  return b;
}

// Single fused kernel: hist/select -> per-bin rank -> decode -> pairs ->
// resolve, separated by grid.sync(). One dispatch: no inter-kernel launch
// or cache-flush boundaries (the R1-R7 ~50-70us/dispatch tax).
__global__ __launch_bounds__(BLK, 4) void k_fused(
    const float* __restrict__ scores, const float* __restrict__ reg,
    const float* __restrict__ xyz, const float* __restrict__ anchor,
    unsigned long long* __restrict__ selkeys, uint32_t* __restrict__ binpack,
    float* __restrict__ ws_score, float* __restrict__ ws_pr,
    float* __restrict__ bev, int* __restrict__ slotidx,
    int* __restrict__ sel_cnt, int* __restrict__ edge_cnt,
    uint32_t* __restrict__ edges, float* __restrict__ out) {
  __shared__ __align__(16) uint32_t POOL[8192];  // 32 KB, reused per phase
  __shared__ uint32_t wsum[4];
  __shared__ int s_bt, s_cnt;
  cg::grid_group grid = cg::this_grid();
  const int gbx = blockIdx.x, tid = threadIdx.x;
  const int lane = tid & 63, wave = tid >> 6;

  // ===== Phase 1: per-image histogram + threshold + bin-grouped compact ====
  if (gbx < BN) {
    const int img = gbx;
    uint32_t* hist = POOL;          // counts -> then per-bin base offsets
    uint32_t* ofs = POOL + NBINS;   // within-bin cursors
    for (int i = tid; i < NBINS; i += BLK) { hist[i] = 0u; ofs[i] = 0u; }
    if (tid == 0) edge_cnt[img] = 0;
    __syncthreads();
    const float* sc = scores + img * NPTS;
    for (int r = 0; r < NPTS / BLK; ++r)
      atomicAdd(&hist[flip_f32(sc[tid + r * BLK]) >> 20], 1u);
    __syncthreads();

    // suffix scan over 4096 bins: thread owns 16 contiguous bins
    uint32_t c[16], ss[17];
    const int b0 = tid * 16;
    ss[16] = 0;
#pragma unroll
    for (int k = 15; k >= 0; --k) { c[k] = hist[b0 + k]; ss[k] = ss[k + 1] + c[k]; }
    const uint32_t tot = ss[0];
    uint32_t run = tot;  // inclusive suffix scan across the wave
#pragma unroll
    for (int off = 1; off < 64; off <<= 1) {
      uint32_t v = __shfl_down(run, off);
      if (lane + off < 64) run += v;
    }
    if (lane == 0) wsum[wave] = run;
    __syncthreads();
    uint32_t tail = 0;
    for (int w = wave + 1; w < 4; ++w) tail += wsum[w];
    const uint32_t after = run - tot + tail;  // suffix strictly after my bins
#pragma unroll
    for (int k = 0; k < 16; ++k) {
      uint32_t Sk = ss[k] + after, Sk1 = ss[k + 1] + after;
      if (Sk >= (uint32_t)PRE && Sk1 < (uint32_t)PRE) {
        s_bt = b0 + k; s_cnt = (int)Sk;
      }
    }
#pragma unroll
    for (int k = 0; k < 16; ++k) {
      uint32_t base = ss[k + 1] + after;  // base(b) = suffix(b+1)
      hist[b0 + k] = base;
      binpack[img * NBINS + b0 + k] = (base << 16) | c[k];
    }
    __syncthreads();
    const int bt = s_bt;
    for (int r = 0; r < NPTS / BLK; ++r) {
      int n = tid + r * BLK;
      uint32_t key = flip_f32(sc[n]);
      int bin = (int)(key >> 20);
      if (bin >= bt) {
        uint32_t pos = hist[bin] + atomicAdd(&ofs[bin], 1u);
        if (pos < SORTN)
          selkeys[img * SORTN + pos] =
              ((unsigned long long)(~key) << 32) | (uint32_t)n;
      }
    }
    if (tid == 0) sel_cnt[img] = s_cnt < SORTN ? s_cnt : SORTN;
  }
  grid.sync();

  // ===== Phase 2: per-bin cooperative rank (grid-stride over img x bin) ====
  {
    unsigned long long* seg = reinterpret_cast<unsigned long long*>(POOL);
    for (int vb = gbx; vb < BN * NBINS; vb += GRID) {
      const int img = vb >> 12;
      const int bin = vb & (NBINS - 1);
      const uint32_t pack = binpack[img * NBINS + bin];
      const int cnt_b = (int)(pack & 0xFFFFu);
      const int base = (int)(pack >> 16);
      const int total = sel_cnt[img];
      if (cnt_b == 0 || base >= total) continue;  // block-uniform
      int end = base + cnt_b;
      end = end < total ? end : total;
      end = end < SORTN ? end : SORTN;
      const int n = end - base;
      if (n <= 0) continue;
      const unsigned long long* kp = selkeys + img * SORTN + base;
      if (n <= SEGCAP) {
        __syncthreads();  // protect seg reuse across loop iterations
        for (int e = tid; e < n; e += BLK) seg[e] = kp[e];
        __syncthreads();
        unsigned long long myk[8];
        int rk[8];
#pragma unroll
        for (int u = 0; u < 8; ++u) {
          int e = tid + u * BLK;
          myk[u] = (e < n) ? seg[e] : ~0ULL;
          rk[u] = 0;
        }
        for (int q = 0; q < n; ++q) {
          unsigned long long kq = seg[q];  // uniform -> LDS broadcast
#pragma unroll
          for (int u = 0; u < 8; ++u) rk[u] += (int)(kq < myk[u]);
        }
#pragma unroll
        for (int u = 0; u < 8; ++u) {
          int e = tid + u * BLK;
          if (e < n) {
            int slot = base + rk[u];  // exact & stable: u64 keys unique
            if (slot < PRE) {
              slotidx[img * PRE_PAD + slot] = (int)(uint32_t)myk[u];
              ws_score[img * PRE_PAD + slot] =
                  unflip_f32(~(uint32_t)(myk[u] >> 32));
            }
          }
        }
      } else {
        // adversarial fallback (bin > SEGCAP): global uniform reads
        for (int e = tid; e < n; e += BLK) {
          unsigned long long mk = kp[e];
          int rk = 0;
          for (int q = 0; q < n; ++q) rk += (int)(kp[q] < mk);
          int slot = base + rk;
          if (slot < PRE) {
            slotidx[img * PRE_PAD + slot] = (int)(uint32_t)mk;
            ws_score[img * PRE_PAD + slot] = unflip_f32(~(uint32_t)(mk >> 32));
          }
        }
      }
    }
  }
  grid.sync();

  // ===== Phase 3: decode (144 blocks x wave0, direct loads, no big array) ==
  if (gbx < (BN * PRE_PAD) / 64 && tid < 64) {
    const int slot = gbx * 64 + tid;
    const int img = slot / PRE_PAD;
    const int r = slot - img * PRE_PAD;
    if (r < PRE) {
      const int idx = slotidx[img * PRE_PAD + r];
      const float* rr = reg + (size_t)(img * NPTS + idx) * REGC;
      const float4* r4 = reinterpret_cast<const float4*>(rr);
      float4 f0 = r4[0], f1 = r4[1], f2 = r4[2];
      float4 f3 = r4[3], f4 = r4[4], f5 = r4[5];
      float va[12] = {f0.x, f0.y, f0.z, f0.w, f1.x, f1.y,
                      f1.z, f1.w, f2.x, f2.y, f2.z, f2.w};
      float vz[12] = {f3.x, f3.y, f3.z, f3.w, f4.x, f4.y,
                      f4.z, f4.w, f5.x, f5.y, f5.z, f5.w};
      int xb = argmax12(va), zb = argmax12(vz);
      float xres = rr[24 + xb];
      float zres = rr[36 + zb];
      float posx = xb * 0.5f + 0.25f - 3.0f + xres * 0.5f;
      float posz = zb * 0.5f + 0.25f - 3.0f + zres * 0.5f;

      const float* xp = xyz + (size_t)(img * NPTS + idx) * 3;
      float X = posx + xp[0];
      float Y = xp[1] + rr[48];
      float Z = posz + xp[2];

      float vr[12];
#pragma unroll
      for (int c = 0; c < 12; ++c) vr[c] = rr[49 + c];
      int ryb = argmax12(vr);
      float ryres = rr[61 + ryb];

      const float APC = 0.5235987755982988f;    // (f32)(2pi/12)
      const float APC2 = 0.2617993877991494f;   // (f32)(pi/12)
      const float TWO_PI_F = 6.283185307179586f;
      const float PI_F = 3.141592653589793f;
      float ry = ryb * APC + ryres * APC2;
      ry = fmodf(ry, TWO_PI_F);
      if (ry < 0.0f) ry += TWO_PI_F;            // floored mod == np/jnp %
      if (ry > PI_F) ry -= TWO_PI_F;

      float ah = anchor[0], aw = anchor[1], al = anchor[2];
      float H = rr[73] * ah + ah;
      float W = rr[74] * aw + aw;
      float L = rr[75] * al + al;
      Y += H * 0.5f;                            // y += h/2

      float* pr = ws_pr + (size_t)(img * PRE_PAD + r) * 7;
      pr[0] = X; pr[1] = Y; pr[2] = Z; pr[3] = H; pr[4] = W; pr[5] = L;
      pr[6] = ry;

      int o = img * PRE_PAD + r;
      float x1 = X - L * 0.5f, x2 = X + L * 0.5f;
      float z1 = Z - W * 0.5f, z2 = Z + W * 0.5f;
      bev[o] = x1;
      bev[SZB + o] = x2;
      bev[2 * SZB + o] = z1;
      bev[3 * SZB + o] = z2;
      bev[4 * SZB + o] = (x2 - x1) * (z2 - z1);
    }
  }
  grid.sync();

  // ===== Phase 4: all-pairs IoU > 0.8 -> sparse edges (grid-stride tiles) ==
  {
    float* fp = reinterpret_cast<float*>(POOL);
    float* rx1 = fp + 0;   float* rx2 = fp + 128;
    float* rz1 = fp + 256; float* rz2 = fp + 384;
    float* ra  = fp + 512;
    float* cx1 = fp + 640; float* cx2 = fp + 768;
    float* cz1 = fp + 896; float* cz2 = fp + 1024;
    float* ca  = fp + 1152;
    for (int tile = gbx; tile < BN * NTRI; tile += GRID) {
      const int img = tile / NTRI;
      int t = tile - img * NTRI;
      int ti = 0, acc = 0;
#pragma unroll
      for (int row = 0; row < TI; ++row) {
        int c = TI - row;
        if (t < acc + c) { ti = row; break; }
        acc += c;
      }
      int tj = ti + (t - acc);
      __syncthreads();  // protect LDS reuse across iterations / phases
      if (tid < 128) {
        int o = img * PRE_PAD + ti * 128 + tid;
        rx1[tid] = bev[o];           rx2[tid] = bev[SZB + o];
        rz1[tid] = bev[2 * SZB + o]; rz2[tid] = bev[3 * SZB + o];
        ra[tid] = bev[4 * SZB + o];
      } else {
        int q = tid - 128;
        int o = img * PRE_PAD + tj * 128 + q;
        cx1[q] = bev[o];             cx2[q] = bev[SZB + o];
        cz1[q] = bev[2 * SZB + o];   cz2[q] = bev[3 * SZB + o];
        ca[q] = bev[4 * SZB + o];
      }
      __syncthreads();
      const int b = tid & 127;
      const int a0 = tid >> 7;
      const float bx1 = cx1[b], bx2 = cx2[b], bz1 = cz1[b], bz2 = cz2[b],
                  bar = ca[b];
      const int j = tj * 128 + b;
      for (int a = a0; a < 128; a += 2) {
        int i = ti * 128 + a;
        if (i < j && j < PRE) {
          float iw = fminf(rx2[a], bx2) - fmaxf(rx1[a], bx1);
          iw = fmaxf(iw, 0.0f);
          float ih = fminf(rz2[a], bz2) - fmaxf(rz1[a], bz1);
          ih = fmaxf(ih, 0.0f);
          float inter = iw * ih;
          float iou = inter / (ra[a] + bar - inter);  // IEEE div, ref-exact
          if (iou > NMS_T) {
            int e = atomicAdd(&edge_cnt[img], 1);
            if (e < ECAP)
              edges[img * ECAP + e] = ((uint32_t)i << 16) | (uint32_t)j;
          }
        }
      }
    }
  }
  grid.sync();

  // ===== Phase 5: greedy-NMS resolve + output (1 block per image) =========
  if (gbx < BN) {
    const int img = gbx;
    uint32_t* sup = POOL;          // 2304 u32
    uint32_t* earr = POOL + 2304;  // 4096 u32
    for (int i = tid; i < PRE; i += BLK) sup[i] = 0u;
    int E = edge_cnt[img];
    E = E < 0 ? 0 : (E > ECAP ? ECAP : E);
    int P2 = 1;
    while (P2 < E) P2 <<= 1;
    for (int e = tid; e < P2; e += BLK)
      earr[e] = (e < E) ? edges[img * ECAP + e] : 0xFFFFFFFFu;
    __syncthreads();
    if (wave == 0) {
      volatile uint32_t* ve = earr;
      for (int k = 2; k <= P2; k <<= 1)
        for (int j = k >> 1; j > 0; j >>= 1)
          for (int t = lane; t < (P2 >> 1); t += 64) {
            int ii = ((t & ~(j - 1)) << 1) | (t & (j - 1));
            int l = ii | j;
            uint32_t a = ve[ii], b = ve[l];
            if ((a > b) == ((ii & k) == 0)) { ve[ii] = b; ve[l] = a; }
          }
      if (lane == 0) {
        volatile uint32_t* vsup = sup;
        for (int e = 0; e < E; ++e) {
          uint32_t u = ve[e];
          uint32_t si = u >> 16, sj = u & 0xFFFFu;
          if (!vsup[si]) vsup[sj] = 1u;  // src-sorted => sup[si] final here
        }
      }
    }
    __syncthreads();

    // ranks: 9 contiguous flags/thread (256*9 = 2304), shfl wave scan
    uint32_t fl[9], pf[9];
    uint32_t acc = 0;
#pragma unroll
    for (int k = 0; k < 9; ++k) {
      int q = tid * 9 + k;
      fl[k] = (q < PRE && !sup[q]) ? 1u : 0u;
      acc += fl[k];
      pf[k] = acc;
    }
    const uint32_t tot = acc;
    uint32_t run = tot;
#pragma unroll
    for (int off = 1; off < 64; off <<= 1) {
      uint32_t v = __shfl_up(run, off);
      if (lane >= off) run += v;
    }
    if (lane == 63) wsum[wave] = run;
    __syncthreads();
    uint32_t wbase = 0, total = 0;
    for (int w = 0; w < 4; ++w) {
      uint32_t t = wsum[w];
      if (w < wave) wbase += t;
      total += t;
    }
    const uint32_t before = wbase + run - tot;

    float* ob = out + (size_t)img * POST * 7;
    float* os = out + (size_t)(BN * POST * 7) + img * POST;
#pragma unroll
    for (int k = 0; k < 9; ++k) {
      if (fl[k]) {
        int rk = (int)(before + pf[k]) - 1;
        if (rk < POST) {
          int q = tid * 9 + k;
          const float* p = ws_pr + (size_t)(img * PRE_PAD + q) * 7;
#pragma unroll
          for (int cc = 0; cc < 7; ++cc) ob[rk * 7 + cc] = p[cc];
          os[rk] = ws_score[img * PRE_PAD + q];
        }
      }
    }
    for (int rk = (int)total + tid; rk < POST; rk += BLK) {
#pragma unroll
      for (int cc = 0; cc < 7; ++cc) ob[rk * 7 + cc] = 0.0f;
      os[rk] = 0.0f;
    }
  }
}

extern "C" void kernel_launch(void* const* d_in, const int* in_sizes, int n_in,
                              void* d_out, int out_size, void* d_ws, size_t ws_size,
                              hipStream_t stream) {
  const float* scores = (const float*)d_in[0];
  const float* reg = (const float*)d_in[1];
  const float* xyz = (const float*)d_in[2];
  const float* anchor = (const float*)d_in[3];
  float* out = (float*)d_out;
  char* ws = (char*)d_ws;

  // workspace layout (bytes); edges aliases selkeys (phase 2 done before 4)
  unsigned long long* selkeys = (unsigned long long*)(ws + 0);  // 131072
  uint32_t* edges = (uint32_t*)(ws + 0);                        // 65536 alias
  uint32_t* binpack = (uint32_t*)(ws + 131072);  // BN*NBINS u32     = 65536
  float* ws_score = (float*)(ws + 196608);       // BN*PRE_PAD f32   = 36864
  float* ws_pr = (float*)(ws + 233472);          // BN*PRE_PAD*7 f32 = 258048
  float* bev = (float*)(ws + 491520);            // 5*SZB f32        = 184320
  int* slotidx = (int*)(ws + 675840);            // BN*PRE_PAD int   = 36864
  int* sel_cnt = (int*)(ws + 712704);            // BN int
  int* edge_cnt = (int*)(ws + 712720);           // BN int

  void* params[] = {&scores, &reg,      &xyz,     &anchor,  &selkeys,
                    &binpack, &ws_score, &ws_pr,   &bev,     &slotidx,
                    &sel_cnt, &edge_cnt, &edges,   &out};
  hipLaunchCooperativeKernel(reinterpret_cast<const void*>(k_fused),
                             dim3(GRID), dim3(BLK), params, 0, stream);
}

// Round 9
// 351.346 us; speedup vs baseline: 1.1733x; 1.1733x over previous
//
#include <hip/hip_runtime.h>
#include <stdint.h>

// ---- problem constants (PointRCNN RPN, KITTI Car) ----
#define BN 4
#define NPTS 16384
#define REGC 76
#define PRE 2250
#define PRE_PAD 2304          // 18*128, padded stride
#define POST 128
#define NBINS 4096            // 12-bit histogram on flipped float key
#define SORTN 4096            // candidate-set capacity (LDS key table)
#define ECAP 4096             // max suppression edges per image
#define NMS_T 0.8f
#define TI 18                 // ceil(PRE/128)
#define NTRI 171              // TI*(TI+1)/2 upper-triangle tiles per image
#define SZB (BN * PRE_PAD)    // per-array stride for BEV SoA

// Order-preserving float->uint flip: ascending uint == ascending float.
__device__ __forceinline__ uint32_t flip_f32(float f) {
  uint32_t u = __float_as_uint(f);
  return (u & 0x80000000u) ? ~u : (u | 0x80000000u);
}
__device__ __forceinline__ float unflip_f32(uint32_t k) {
  uint32_t u = (k & 0x80000000u) ? (k & 0x7FFFFFFFu) : ~k;
  return __uint_as_float(u);
}
__device__ __forceinline__ int argmax12(const float* a) {
  int b = 0;
  float m = a[0];
#pragma unroll
  for (int c = 1; c < 12; ++c)
    if (a[c] > m) { m = a[c]; b = c; }   // strict > == first-occurrence argmax
  return b;
}

// Kernel 1 (grid = BN, 1024 thr): everything per-image that fits one block.
// Phase A: 12-bit histogram + threshold + bin-grouped compact INTO LDS.
// Phase B: per-wave bin rank from the LDS key table (broadcast reads).
// Phase C: decode via direct divergent loads (16 waves hide latency).
__global__ __launch_bounds__(1024) void k_front(
    const float* __restrict__ scores, const float* __restrict__ reg,
    const float* __restrict__ xyz, const float* __restrict__ anchor,
    float* __restrict__ ws_score, float* __restrict__ ws_pr,
    float* __restrict__ bev, int* __restrict__ slotidx,
    int* __restrict__ edge_cnt, int* __restrict__ done_cnt) {
  __shared__ uint32_t hist[NBINS];                 // counts -> bin bases 16 KB
  __shared__ uint32_t ofs[NBINS];                  // bin cursors/counts  16 KB
  __shared__ unsigned long long sel[SORTN];        // compacted keys      32 KB
  __shared__ uint32_t wsum[16];
  __shared__ int s_bt, s_cnt;
  const int img = blockIdx.x, tid = threadIdx.x;
  const int wave = tid >> 6, lane = tid & 63;
  const float* sc = scores + img * NPTS;

  // ---- Phase A: histogram + suffix-scan threshold + compact ----
  for (int i = tid; i < NBINS; i += 1024) { hist[i] = 0u; ofs[i] = 0u; }
  if (tid == 0) { edge_cnt[img] = 0; done_cnt[img] = 0; }
  __syncthreads();

  uint32_t k0[16];
#pragma unroll
  for (int r = 0; r < 16; ++r) {
    k0[r] = flip_f32(sc[tid + r * 1024]);
    atomicAdd(&hist[k0[r] >> 20], 1u);
  }
  __syncthreads();

  // suffix counts: thread owns 4 contiguous bins [4t, 4t+3]
  const uint32_t c0 = hist[4 * tid + 0], c1 = hist[4 * tid + 1];
  const uint32_t c2 = hist[4 * tid + 2], c3 = hist[4 * tid + 3];
  uint32_t s3 = c3, s2 = c2 + s3, s1 = c1 + s2, s0 = c0 + s1;
  const uint32_t tot = s0;
  uint32_t run = tot;  // inclusive suffix scan across wave (right-to-left)
#pragma unroll
  for (int off = 1; off < 64; off <<= 1) {
    uint32_t v = __shfl_down(run, off);
    if (lane + off < 64) run += v;
  }
  if (lane == 0) wsum[wave] = run;
  __syncthreads();
  uint32_t tail = 0;
  for (int w = wave + 1; w < 16; ++w) tail += wsum[w];
  const uint32_t after = run - tot + tail;  // suffix strictly after my bins
  const uint32_t S0 = s0 + after, S1 = s1 + after, S2 = s2 + after,
                 S3 = s3 + after;
  const uint32_t P = PRE;
  if (S0 >= P && S1 < P) { s_bt = 4 * tid + 0; s_cnt = (int)S0; }
  if (S1 >= P && S2 < P) { s_bt = 4 * tid + 1; s_cnt = (int)S1; }
  if (S2 >= P && S3 < P) { s_bt = 4 * tid + 2; s_cnt = (int)S2; }
  if (S3 >= P && after < P) { s_bt = 4 * tid + 3; s_cnt = (int)S3; }
  // overwrite hist with per-bin base offsets: base(b) = suffix(b+1)
  hist[4 * tid + 0] = S1;
  hist[4 * tid + 1] = S2;
  hist[4 * tid + 2] = S3;
  hist[4 * tid + 3] = after;
  __syncthreads();
  const int bt = s_bt;

#pragma unroll
  for (int r = 0; r < 16; ++r) {
    const int bin = (int)(k0[r] >> 20);
    if (bin >= bt) {
      uint32_t pos = hist[bin] + atomicAdd(&ofs[bin], 1u);
      if (pos < SORTN)
        sel[pos] =
            ((unsigned long long)(~k0[r]) << 32) | (uint32_t)(tid + r * 1024);
    }
  }
  __syncthreads();

  // ---- Phase B: per-wave bin rank from LDS (broadcast reads) ----
  // wave w handles bins b = bt+w, bt+w+16, ... ; ofs[b] = #compacted in bin.
  for (int b = bt + wave; b < NBINS; b += 16) {
    const int nb = (int)ofs[b];
    if (nb == 0) continue;
    const int base = (int)hist[b];
    if (base >= SORTN) continue;
    int end = base + nb;
    end = end < SORTN ? end : SORTN;
    const int n = end - base;
    // lane owns elems e = lane, lane+64, ... (max 4096/64 = 64, real ~8)
    for (int e0 = 0; e0 * 64 + lane < n; ++e0) {
      const int e = base + e0 * 64 + lane;
      const unsigned long long myk = sel[e];
      int rk = 0;
      for (int q = base; q < end; ++q) rk += (int)(sel[q] < myk);  // broadcast
      const int slot = base + rk;  // exact & stable: u64 keys unique
      if (slot < PRE) {
        slotidx[img * PRE_PAD + slot] = (int)(uint32_t)myk;
        ws_score[img * PRE_PAD + slot] = unflip_f32(~(uint32_t)(myk >> 32));
      }
    }
  }
  __syncthreads();  // drains vmcnt: slotidx visible block-wide

  // ---- Phase C: decode (direct loads; 16 waves hide gather latency) ----
  for (int r = tid; r < PRE; r += 1024) {
    const int idx = slotidx[img * PRE_PAD + r];
    const float* rr = reg + (size_t)(img * NPTS + idx) * REGC;
    const float4* r4 = reinterpret_cast<const float4*>(rr);
    float4 f0 = r4[0], f1 = r4[1], f2 = r4[2];
    float4 f3 = r4[3], f4 = r4[4], f5 = r4[5];
    float va[12] = {f0.x, f0.y, f0.z, f0.w, f1.x, f1.y,
                    f1.z, f1.w, f2.x, f2.y, f2.z, f2.w};
    float vz[12] = {f3.x, f3.y, f3.z, f3.w, f4.x, f4.y,
                    f4.z, f4.w, f5.x, f5.y, f5.z, f5.w};
    int xb = argmax12(va), zb = argmax12(vz);
    float xres = rr[24 + xb];
    float zres = rr[36 + zb];
    float posx = xb * 0.5f + 0.25f - 3.0f + xres * 0.5f;
    float posz = zb * 0.5f + 0.25f - 3.0f + zres * 0.5f;

    const float* xp = xyz + (size_t)(img * NPTS + idx) * 3;
    float X = posx + xp[0];
    float Y = xp[1] + rr[48];
    float Z = posz + xp[2];

    float vr[12];
#pragma unroll
    for (int c = 0; c < 12; ++c) vr[c] = rr[49 + c];
    int ryb = argmax12(vr);
    float ryres = rr[61 + ryb];

    const float APC = 0.5235987755982988f;    // (f32)(2pi/12)
    const float APC2 = 0.2617993877991494f;   // (f32)(pi/12)
    const float TWO_PI_F = 6.283185307179586f;
    const float PI_F = 3.141592653589793f;
    float ry = ryb * APC + ryres * APC2;
    ry = fmodf(ry, TWO_PI_F);
    if (ry < 0.0f) ry += TWO_PI_F;            // floored mod == np/jnp %
    if (ry > PI_F) ry -= TWO_PI_F;

    float ah = anchor[0], aw = anchor[1], al = anchor[2];
    float H = rr[73] * ah + ah;
    float W = rr[74] * aw + aw;
    float L = rr[75] * al + al;
    Y += H * 0.5f;                            // y += h/2

    float* pr = ws_pr + (size_t)(img * PRE_PAD + r) * 7;
    pr[0] = X; pr[1] = Y; pr[2] = Z; pr[3] = H; pr[4] = W; pr[5] = L;
    pr[6] = ry;

    int o = img * PRE_PAD + r;
    float x1 = X - L * 0.5f, x2 = X + L * 0.5f;
    float z1 = Z - W * 0.5f, z2 = Z + W * 0.5f;
    bev[o] = x1;
    bev[SZB + o] = x2;
    bev[2 * SZB + o] = z1;
    bev[3 * SZB + o] = z2;
    bev[4 * SZB + o] = (x2 - x1) * (z2 - z1);
  }
}

// Kernel 2 (grid = BN*NTRI, 256 thr): pairs IoU>0.8 -> edges; the LAST
// block per image (device-scope done-counter, fence, no spinning) then
// runs greedy-NMS resolve + output emission in the same dispatch.
__global__ __launch_bounds__(256) void k_back(
    const float* __restrict__ bev, const float* __restrict__ ws_pr,
    const float* __restrict__ ws_score, uint32_t* __restrict__ edges,
    int* __restrict__ edge_cnt, int* __restrict__ done_cnt,
    float* __restrict__ out) {
  __shared__ float rx1[128], rx2[128], rz1[128], rz2[128], ra[128];
  __shared__ float cx1[128], cx2[128], cz1[128], cz2[128], ca[128];
  __shared__ uint32_t sup[PRE_PAD];   // 9.2 KB (resolve)
  __shared__ uint32_t earr[ECAP];     // 16 KB (resolve)
  __shared__ uint32_t wsum4[4];
  __shared__ int sh_last;
  const int tile = blockIdx.x, tid = threadIdx.x;
  const int wave = tid >> 6, lane = tid & 63;
  const int img = tile / NTRI;
  int t = tile - img * NTRI;
  int ti = 0, acc = 0;
#pragma unroll
  for (int row = 0; row < TI; ++row) {
    int c = TI - row;
    if (t < acc + c) { ti = row; break; }
    acc += c;
  }
  int tj = ti + (t - acc);

  if (tid < 128) {
    int o = img * PRE_PAD + ti * 128 + tid;
    rx1[tid] = bev[o];           rx2[tid] = bev[SZB + o];
    rz1[tid] = bev[2 * SZB + o]; rz2[tid] = bev[3 * SZB + o];
    ra[tid] = bev[4 * SZB + o];
  } else {
    int q = tid - 128;
    int o = img * PRE_PAD + tj * 128 + q;
    cx1[q] = bev[o];             cx2[q] = bev[SZB + o];
    cz1[q] = bev[2 * SZB + o];   cz2[q] = bev[3 * SZB + o];
    ca[q] = bev[4 * SZB + o];
  }
  __syncthreads();

  {
    const int b = tid & 127;
    const int a0 = tid >> 7;
    const float bx1 = cx1[b], bx2 = cx2[b], bz1 = cz1[b], bz2 = cz2[b],
                bar = ca[b];
    const int j = tj * 128 + b;
    for (int a = a0; a < 128; a += 2) {
      int i = ti * 128 + a;
      if (i < j && j < PRE) {
        float iw = fminf(rx2[a], bx2) - fmaxf(rx1[a], bx1);
        iw = fmaxf(iw, 0.0f);
        float ih = fminf(rz2[a], bz2) - fmaxf(rz1[a], bz1);
        ih = fmaxf(ih, 0.0f);
        float inter = iw * ih;
        float iou = inter / (ra[a] + bar - inter);  // IEEE div, ref-exact
        if (iou > NMS_T) {
          int e = atomicAdd(&edge_cnt[img], 1);
          if (e < ECAP)
            edges[img * ECAP + e] = ((uint32_t)i << 16) | (uint32_t)j;
        }
      }
    }
  }
  // ---- last-block election (no spinning; dispatch-order independent) ----
  __threadfence();                       // release my edge writes
  __syncthreads();
  if (tid == 0) {
    int old = atomicAdd(&done_cnt[img], 1);
    sh_last = (old == NTRI - 1);
  }
  __syncthreads();
  if (!sh_last) return;
  __threadfence();                       // acquire all images' edge writes

  // ---- resolve (256 threads): sort edges, greedy walk, rank, emit ----
  int E = *((volatile int*)&edge_cnt[img]);
  E = E < 0 ? 0 : (E > ECAP ? ECAP : E);
  int P2 = 1;
  while (P2 < E) P2 <<= 1;
  for (int i = tid; i < PRE_PAD; i += 256) sup[i] = 0u;
  for (int e = tid; e < P2; e += 256)
    earr[e] = (e < E) ? *((volatile uint32_t*)&edges[img * ECAP + e])
                      : 0xFFFFFFFFu;
  __syncthreads();

  if (wave == 0) {
    volatile uint32_t* ve = earr;
    for (int k = 2; k <= P2; k <<= 1)
      for (int j = k >> 1; j > 0; j >>= 1)
        for (int tt = lane; tt < (P2 >> 1); tt += 64) {
          int ii = ((tt & ~(j - 1)) << 1) | (tt & (j - 1));
          int l = ii | j;
          uint32_t a = ve[ii], b = ve[l];
          if ((a > b) == ((ii & k) == 0)) { ve[ii] = b; ve[l] = a; }
        }
    if (lane == 0) {
      volatile uint32_t* vsup = sup;
      for (int e = 0; e < E; ++e) {
        uint32_t u = ve[e];
        uint32_t si = u >> 16, sj = u & 0xFFFFu;
        if (!vsup[si]) vsup[sj] = 1u;  // src-sorted => sup[si] final here
      }
    }
  }
  __syncthreads();

  // ranks: 9 contiguous flags/thread (256*9 = 2304 >= PRE), shfl wave scan
  uint32_t fl[9], pf[9];
  uint32_t accf = 0;
#pragma unroll
  for (int k = 0; k < 9; ++k) {
    int q = tid * 9 + k;
    fl[k] = (q < PRE && !sup[q]) ? 1u : 0u;
    accf += fl[k];
    pf[k] = accf;
  }
  const uint32_t totf = accf;
  uint32_t run = totf;
#pragma unroll
  for (int off = 1; off < 64; off <<= 1) {
    uint32_t v = __shfl_up(run, off);
    if (lane >= off) run += v;
  }
  if (lane == 63) wsum4[wave] = run;
  __syncthreads();
  uint32_t wbase = 0, total = 0;
  for (int w = 0; w < 4; ++w) {
    uint32_t tv = wsum4[w];
    if (w < wave) wbase += tv;
    total += tv;
  }
  const uint32_t before = wbase + run - totf;

  float* ob = out + (size_t)img * POST * 7;
  float* os = out + (size_t)(BN * POST * 7) + img * POST;
#pragma unroll
  for (int k = 0; k < 9; ++k) {
    if (fl[k]) {
      int rk = (int)(before + pf[k]) - 1;
      if (rk < POST) {
        int q = tid * 9 + k;
        const float* p = ws_pr + (size_t)(img * PRE_PAD + q) * 7;
#pragma unroll
        for (int cc = 0; cc < 7; ++cc) ob[rk * 7 + cc] = p[cc];
        os[rk] = ws_score[img * PRE_PAD + q];
      }
    }
  }
  for (int rk = (int)total + tid; rk < POST; rk += 256) {
#pragma unroll
    for (int cc = 0; cc < 7; ++cc) ob[rk * 7 + cc] = 0.0f;
    os[rk] = 0.0f;
  }
}

extern "C" void kernel_launch(void* const* d_in, const int* in_sizes, int n_in,
                              void* d_out, int out_size, void* d_ws, size_t ws_size,
                              hipStream_t stream) {
  const float* scores = (const float*)d_in[0];
  const float* reg = (const float*)d_in[1];
  const float* xyz = (const float*)d_in[2];
  const float* anchor = (const float*)d_in[3];
  float* out = (float*)d_out;
  char* ws = (char*)d_ws;

  // workspace layout (bytes)
  float* ws_score = (float*)(ws + 0);         // BN*PRE_PAD f32   = 36864
  float* ws_pr = (float*)(ws + 36864);        // BN*PRE_PAD*7 f32 = 258048
  float* bev = (float*)(ws + 294912);         // 5*SZB f32        = 184320
  int* slotidx = (int*)(ws + 479232);         // BN*PRE_PAD int   = 36864
  uint32_t* edges = (uint32_t*)(ws + 516096); // BN*ECAP u32      = 65536
  int* edge_cnt = (int*)(ws + 581632);        // BN int
  int* done_cnt = (int*)(ws + 581648);        // BN int

  k_front<<<BN, 1024, 0, stream>>>(scores, reg, xyz, anchor, ws_score, ws_pr,
                                   bev, slotidx, edge_cnt, done_cnt);
  k_back<<<BN * NTRI, 256, 0, stream>>>(bev, ws_pr, ws_score, edges, edge_cnt,
                                        done_cnt, out);
}

// Round 10
// 256.702 us; speedup vs baseline: 1.6059x; 1.3687x over previous
//
#include <hip/hip_runtime.h>
#include <stdint.h>

// ---- problem constants (PointRCNN RPN, KITTI Car) ----
#define BN 4
#define NPTS 16384
#define REGC 76
#define PRE 2250
#define PRE_PAD 2304          // 18*128, padded stride
#define POST 128
#define NBINS 4096            // 12-bit histogram on flipped float key
#define SORTN 4096            // candidate-set capacity (LDS key table)
#define ECAP 4096             // max suppression edges per image
#define NMS_T 0.8f
#define TI 18                 // ceil(PRE/128)
#define NTRI 171              // TI*(TI+1)/2 upper-triangle tiles per image
#define SZB (BN * PRE_PAD)    // per-array stride for BEV SoA

// Order-preserving float->uint flip: ascending uint == ascending float.
__device__ __forceinline__ uint32_t flip_f32(float f) {
  uint32_t u = __float_as_uint(f);
  return (u & 0x80000000u) ? ~u : (u | 0x80000000u);
}
__device__ __forceinline__ float unflip_f32(uint32_t k) {
  uint32_t u = (k & 0x80000000u) ? (k & 0x7FFFFFFFu) : ~k;
  return __uint_as_float(u);
}
__device__ __forceinline__ int argmax12(const float* a) {
  int b = 0;
  float m = a[0];
#pragma unroll
  for (int c = 1; c < 12; ++c)
    if (a[c] > m) { m = a[c]; b = c; }   // strict > == first-occurrence argmax
  return b;
}

// Kernel 1 (grid = BN, 1024 thr): selection + exact stable rank, all in LDS.
// NO decode here — decode's divergent gathers need a spread grid (R9 lesson:
// 26 gathers x 2250 rows on 4 CUs = ~200us of TA throughput).
__global__ __launch_bounds__(1024) void k_front(
    const float* __restrict__ scores, float* __restrict__ ws_score,
    int* __restrict__ slotidx, int* __restrict__ edge_cnt,
    int* __restrict__ done_cnt) {
  __shared__ uint32_t hist[NBINS];                 // counts -> bin bases 16 KB
  __shared__ uint32_t ofs[NBINS];                  // bin cursors/counts  16 KB
  __shared__ unsigned long long sel[SORTN];        // compacted keys      32 KB
  __shared__ uint32_t wsum[16];
  __shared__ int bigbins[64];
  __shared__ int s_bt, s_nbig;
  const int img = blockIdx.x, tid = threadIdx.x;
  const int wave = tid >> 6, lane = tid & 63;
  const float* sc = scores + img * NPTS;

  // ---- Phase A: histogram + suffix-scan threshold + bin-grouped compact ---
  for (int i = tid; i < NBINS; i += 1024) { hist[i] = 0u; ofs[i] = 0u; }
  if (tid == 0) { edge_cnt[img] = 0; done_cnt[img] = 0; s_nbig = 0; }
  __syncthreads();

  uint32_t k0[16];
#pragma unroll
  for (int r = 0; r < 16; ++r) {
    k0[r] = flip_f32(sc[tid + r * 1024]);
    atomicAdd(&hist[k0[r] >> 20], 1u);
  }
  __syncthreads();

  // suffix counts: thread owns 4 contiguous bins [4t, 4t+3]
  const uint32_t c0 = hist[4 * tid + 0], c1 = hist[4 * tid + 1];
  const uint32_t c2 = hist[4 * tid + 2], c3 = hist[4 * tid + 3];
  uint32_t s3 = c3, s2 = c2 + s3, s1 = c1 + s2, s0 = c0 + s1;
  const uint32_t tot = s0;
  uint32_t run = tot;  // inclusive suffix scan across wave (right-to-left)
#pragma unroll
  for (int off = 1; off < 64; off <<= 1) {
    uint32_t v = __shfl_down(run, off);
    if (lane + off < 64) run += v;
  }
  if (lane == 0) wsum[wave] = run;
  __syncthreads();
  uint32_t tail = 0;
  for (int w = wave + 1; w < 16; ++w) tail += wsum[w];
  const uint32_t after = run - tot + tail;  // suffix strictly after my bins
  const uint32_t S0 = s0 + after, S1 = s1 + after, S2 = s2 + after,
                 S3 = s3 + after;
  const uint32_t P = PRE;
  if (S0 >= P && S1 < P) s_bt = 4 * tid + 0;
  if (S1 >= P && S2 < P) s_bt = 4 * tid + 1;
  if (S2 >= P && S3 < P) s_bt = 4 * tid + 2;
  if (S3 >= P && after < P) s_bt = 4 * tid + 3;
  // overwrite hist with per-bin base offsets: base(b) = suffix(b+1)
  hist[4 * tid + 0] = S1;
  hist[4 * tid + 1] = S2;
  hist[4 * tid + 2] = S3;
  hist[4 * tid + 3] = after;
  __syncthreads();
  const int bt = s_bt;

#pragma unroll
  for (int r = 0; r < 16; ++r) {
    const int bin = (int)(k0[r] >> 20);
    if (bin >= bt) {
      uint32_t pos = hist[bin] + atomicAdd(&ofs[bin], 1u);
      if (pos < SORTN)
        sel[pos] =
            ((unsigned long long)(~k0[r]) << 32) | (uint32_t)(tid + r * 1024);
    }
  }
  __syncthreads();

  // ---- Phase B: per-bin rank (exact & stable; u64 keys unique) ----
  // small bins (n<=64): one wave-lane per element, broadcast inner loop.
  // big bins (n>64, e.g. the ~450-elem threshold bin): deferred to a
  // block-cooperative pass so one wave doesn't serialize ~3K iterations.
  for (int b = bt + wave; b < NBINS; b += 16) {
    const int nb = (int)ofs[b];
    if (nb == 0) continue;
    const int base = (int)hist[b];
    if (base >= SORTN) continue;
    int end = base + nb;
    end = end < SORTN ? end : SORTN;
    const int n = end - base;
    if (n > 64) {
      if (lane == 0) {
        int p = atomicAdd(&s_nbig, 1);
        if (p < 64) bigbins[p] = b;
      }
      continue;
    }
    if (lane < n) {
      const int e = base + lane;
      const unsigned long long myk = sel[e];
      int rk = 0;
      for (int q = base; q < end; ++q) rk += (int)(sel[q] < myk);  // broadcast
      const int slot = base + rk;
      if (slot < PRE) {
        slotidx[img * PRE_PAD + slot] = (int)(uint32_t)myk;
        ws_score[img * PRE_PAD + slot] = unflip_f32(~(uint32_t)(myk >> 32));
      }
    }
  }
  __syncthreads();
  const int nbig = s_nbig < 64 ? s_nbig : 64;
  for (int bb = 0; bb < nbig; ++bb) {
    const int b = bigbins[bb];
    const int base = (int)hist[b];
    int end = base + (int)ofs[b];
    end = end < SORTN ? end : SORTN;
    for (int e = base + tid; e < end; e += 1024) {
      const unsigned long long myk = sel[e];
      int rk = 0;
      for (int q = base; q < end; ++q) rk += (int)(sel[q] < myk);  // broadcast
      const int slot = base + rk;
      if (slot < PRE) {
        slotidx[img * PRE_PAD + slot] = (int)(uint32_t)myk;
        ws_score[img * PRE_PAD + slot] = unflip_f32(~(uint32_t)(myk >> 32));
      }
    }
  }
}

// Kernel 2 (grid = BN*PRE_PAD/64, 64 thr): decode, one thread per sorted
// slot, spread across CUs so divergent gathers are latency-hidden (R7: this
// exact shape never appeared in the top-5).
__global__ __launch_bounds__(64) void k_decode(
    const int* __restrict__ slotidx, const float* __restrict__ reg,
    const float* __restrict__ xyz, const float* __restrict__ anchor,
    float* __restrict__ ws_pr, float* __restrict__ bev) {
  const int slot = blockIdx.x * 64 + threadIdx.x;
  const int img = slot / PRE_PAD;
  const int r = slot - img * PRE_PAD;
  if (r >= PRE) return;
  const int idx = slotidx[img * PRE_PAD + r];
  const float* rr = reg + (size_t)(img * NPTS + idx) * REGC;
  const float4* r4 = reinterpret_cast<const float4*>(rr);
  float4 f0 = r4[0], f1 = r4[1], f2 = r4[2];
  float4 f3 = r4[3], f4 = r4[4], f5 = r4[5];
  float va[12] = {f0.x, f0.y, f0.z, f0.w, f1.x, f1.y,
                  f1.z, f1.w, f2.x, f2.y, f2.z, f2.w};
  float vz[12] = {f3.x, f3.y, f3.z, f3.w, f4.x, f4.y,
                  f4.z, f4.w, f5.x, f5.y, f5.z, f5.w};
  int xb = argmax12(va), zb = argmax12(vz);
  float xres = rr[24 + xb];
  float zres = rr[36 + zb];
  float posx = xb * 0.5f + 0.25f - 3.0f + xres * 0.5f;
  float posz = zb * 0.5f + 0.25f - 3.0f + zres * 0.5f;

  const float* xp = xyz + (size_t)(img * NPTS + idx) * 3;
  float X = posx + xp[0];
  float Y = xp[1] + rr[48];
  float Z = posz + xp[2];

  float vr[12];
#pragma unroll
  for (int c = 0; c < 12; ++c) vr[c] = rr[49 + c];
  int ryb = argmax12(vr);
  float ryres = rr[61 + ryb];

  const float APC = 0.5235987755982988f;    // (f32)(2pi/12)
  const float APC2 = 0.2617993877991494f;   // (f32)(pi/12)
  const float TWO_PI_F = 6.283185307179586f;
  const float PI_F = 3.141592653589793f;
  float ry = ryb * APC + ryres * APC2;
  ry = fmodf(ry, TWO_PI_F);
  if (ry < 0.0f) ry += TWO_PI_F;            // floored mod == np/jnp %
  if (ry > PI_F) ry -= TWO_PI_F;

  float ah = anchor[0], aw = anchor[1], al = anchor[2];
  float H = rr[73] * ah + ah;
  float W = rr[74] * aw + aw;
  float L = rr[75] * al + al;
  Y += H * 0.5f;                            // y += h/2

  float* pr = ws_pr + (size_t)(img * PRE_PAD + r) * 7;
  pr[0] = X; pr[1] = Y; pr[2] = Z; pr[3] = H; pr[4] = W; pr[5] = L; pr[6] = ry;

  int o = img * PRE_PAD + r;
  float x1 = X - L * 0.5f, x2 = X + L * 0.5f;
  float z1 = Z - W * 0.5f, z2 = Z + W * 0.5f;
  bev[o] = x1;
  bev[SZB + o] = x2;
  bev[2 * SZB + o] = z1;
  bev[3 * SZB + o] = z2;
  bev[4 * SZB + o] = (x2 - x1) * (z2 - z1);
}

// Kernel 3 (grid = BN*NTRI, 256 thr): pairs IoU>0.8 -> edges; the LAST
// block per image (device-scope done-counter, fence, no spinning) then
// runs greedy-NMS resolve + output emission in the same dispatch.
__global__ __launch_bounds__(256) void k_back(
    const float* __restrict__ bev, const float* __restrict__ ws_pr,
    const float* __restrict__ ws_score, uint32_t* __restrict__ edges,
    int* __restrict__ edge_cnt, int* __restrict__ done_cnt,
    float* __restrict__ out) {
  __shared__ float rx1[128], rx2[128], rz1[128], rz2[128], ra[128];
  __shared__ float cx1[128], cx2[128], cz1[128], cz2[128], ca[128];
  __shared__ uint32_t sup[PRE_PAD];   // 9.2 KB (resolve)
  __shared__ uint32_t earr[ECAP];     // 16 KB (resolve)
  __shared__ uint32_t wsum4[4];
  __shared__ int sh_last;
  const int tile = blockIdx.x, tid = threadIdx.x;
  const int wave = tid >> 6, lane = tid & 63;
  const int img = tile / NTRI;
  int t = tile - img * NTRI;
  int ti = 0, acc = 0;
#pragma unroll
  for (int row = 0; row < TI; ++row) {
    int c = TI - row;
    if (t < acc + c) { ti = row; break; }
    acc += c;
  }
  int tj = ti + (t - acc);

  if (tid < 128) {
    int o = img * PRE_PAD + ti * 128 + tid;
    rx1[tid] = bev[o];           rx2[tid] = bev[SZB + o];
    rz1[tid] = bev[2 * SZB + o]; rz2[tid] = bev[3 * SZB + o];
    ra[tid] = bev[4 * SZB + o];
  } else {
    int q = tid - 128;
    int o = img * PRE_PAD + tj * 128 + q;
    cx1[q] = bev[o];             cx2[q] = bev[SZB + o];
    cz1[q] = bev[2 * SZB + o];   cz2[q] = bev[3 * SZB + o];
    ca[q] = bev[4 * SZB + o];
  }
  __syncthreads();

  {
    const int b = tid & 127;
    const int a0 = tid >> 7;
    const float bx1 = cx1[b], bx2 = cx2[b], bz1 = cz1[b], bz2 = cz2[b],
                bar = ca[b];
    const int j = tj * 128 + b;
    for (int a = a0; a < 128; a += 2) {
      int i = ti * 128 + a;
      if (i < j && j < PRE) {
        float iw = fminf(rx2[a], bx2) - fmaxf(rx1[a], bx1);
        iw = fmaxf(iw, 0.0f);
        float ih = fminf(rz2[a], bz2) - fmaxf(rz1[a], bz1);
        ih = fmaxf(ih, 0.0f);
        float inter = iw * ih;
        float iou = inter / (ra[a] + bar - inter);  // IEEE div, ref-exact
        if (iou > NMS_T) {
          int e = atomicAdd(&edge_cnt[img], 1);
          if (e < ECAP)
            edges[img * ECAP + e] = ((uint32_t)i << 16) | (uint32_t)j;
        }
      }
    }
  }
  // ---- last-block election (no spinning; dispatch-order independent) ----
  __threadfence();                       // release my edge writes
  __syncthreads();
  if (tid == 0) {
    int old = atomicAdd(&done_cnt[img], 1);
    sh_last = (old == NTRI - 1);
  }
  __syncthreads();
  if (!sh_last) return;
  __threadfence();                       // acquire all images' edge writes

  // ---- resolve (256 threads): sort edges, greedy walk, rank, emit ----
  int E = *((volatile int*)&edge_cnt[img]);
  E = E < 0 ? 0 : (E > ECAP ? ECAP : E);
  int P2 = 1;
  while (P2 < E) P2 <<= 1;
  for (int i = tid; i < PRE_PAD; i += 256) sup[i] = 0u;
  for (int e = tid; e < P2; e += 256)
    earr[e] = (e < E) ? *((volatile uint32_t*)&edges[img * ECAP + e])
                      : 0xFFFFFFFFu;
  __syncthreads();

  if (wave == 0) {
    volatile uint32_t* ve = earr;
    for (int k = 2; k <= P2; k <<= 1)
      for (int j = k >> 1; j > 0; j >>= 1)
        for (int tt = lane; tt < (P2 >> 1); tt += 64) {
          int ii = ((tt & ~(j - 1)) << 1) | (tt & (j - 1));
          int l = ii | j;
          uint32_t a = ve[ii], b = ve[l];
          if ((a > b) == ((ii & k) == 0)) { ve[ii] = b; ve[l] = a; }
        }
    if (lane == 0) {
      volatile uint32_t* vsup = sup;
      for (int e = 0; e < E; ++e) {
        uint32_t u = ve[e];
        uint32_t si = u >> 16, sj = u & 0xFFFFu;
        if (!vsup[si]) vsup[sj] = 1u;  // src-sorted => sup[si] final here
      }
    }
  }
  __syncthreads();

  // ranks: 9 contiguous flags/thread (256*9 = 2304 >= PRE), shfl wave scan
  uint32_t fl[9], pf[9];
  uint32_t accf = 0;
#pragma unroll
  for (int k = 0; k < 9; ++k) {
    int q = tid * 9 + k;
    fl[k] = (q < PRE && !sup[q]) ? 1u : 0u;
    accf += fl[k];
    pf[k] = accf;
  }
  const uint32_t totf = accf;
  uint32_t run = totf;
#pragma unroll
  for (int off = 1; off < 64; off <<= 1) {
    uint32_t v = __shfl_up(run, off);
    if (lane >= off) run += v;
  }
  if (lane == 63) wsum4[wave] = run;
  __syncthreads();
  uint32_t wbase = 0, total = 0;
  for (int w = 0; w < 4; ++w) {
    uint32_t tv = wsum4[w];
    if (w < wave) wbase += tv;
    total += tv;
  }
  const uint32_t before = wbase + run - totf;

  float* ob = out + (size_t)img * POST * 7;
  float* os = out + (size_t)(BN * POST * 7) + img * POST;
#pragma unroll
  for (int k = 0; k < 9; ++k) {
    if (fl[k]) {
      int rk = (int)(before + pf[k]) - 1;
      if (rk < POST) {
        int q = tid * 9 + k;
        const float* p = ws_pr + (size_t)(img * PRE_PAD + q) * 7;
#pragma unroll
        for (int cc = 0; cc < 7; ++cc) ob[rk * 7 + cc] = p[cc];
        os[rk] = ws_score[img * PRE_PAD + q];
      }
    }
  }
  for (int rk = (int)total + tid; rk < POST; rk += 256) {
#pragma unroll
    for (int cc = 0; cc < 7; ++cc) ob[rk * 7 + cc] = 0.0f;
    os[rk] = 0.0f;
  }
}

extern "C" void kernel_launch(void* const* d_in, const int* in_sizes, int n_in,
                              void* d_out, int out_size, void* d_ws, size_t ws_size,
                              hipStream_t stream) {
  const float* scores = (const float*)d_in[0];
  const float* reg = (const float*)d_in[1];
  const float* xyz = (const float*)d_in[2];
  const float* anchor = (const float*)d_in[3];
  float* out = (float*)d_out;
  char* ws = (char*)d_ws;

  // workspace layout (bytes)
  float* ws_score = (float*)(ws + 0);         // BN*PRE_PAD f32   = 36864
  float* ws_pr = (float*)(ws + 36864);        // BN*PRE_PAD*7 f32 = 258048
  float* bev = (float*)(ws + 294912);         // 5*SZB f32        = 184320
  int* slotidx = (int*)(ws + 479232);         // BN*PRE_PAD int   = 36864
  uint32_t* edges = (uint32_t*)(ws + 516096); // BN*ECAP u32      = 65536
  int* edge_cnt = (int*)(ws + 581632);        // BN int
  int* done_cnt = (int*)(ws + 581648);        // BN int

  k_front<<<BN, 1024, 0, stream>>>(scores, ws_score, slotidx, edge_cnt,
                                   done_cnt);
  k_decode<<<(BN * PRE_PAD) / 64, 64, 0, stream>>>(slotidx, reg, xyz, anchor,
                                                   ws_pr, bev);
  k_back<<<BN * NTRI, 256, 0, stream>>>(bev, ws_pr, ws_score, edges, edge_cnt,
                                        done_cnt, out);
}